// Round 2
// baseline (1228.395 us; speedup 1.0000x reference)
//
#include <hip/hip_runtime.h>
#include <math.h>

#define TT 1024
#define BB 16
#define CC 1024
#define HH 16
#define KK 7
#define PADL 6
#define HK 112          // H*K
#define LSTRIDE 116     // logits LDS row stride (floats)

typedef short bf16x8 __attribute__((ext_vector_type(8)));
typedef float f32x4 __attribute__((ext_vector_type(4)));

__device__ __forceinline__ short f2bf(float f) {
    union { float f; unsigned u; } v; v.f = f;
    unsigned r = v.u + 0x7fff + ((v.u >> 16) & 1);   // RNE; inputs finite
    return (short)(r >> 16);
}

// ---------------------------------------------------------------------------
// K0: W (112x1024 fp32) -> Wb (bf16). 114688 elems = 56 blocks x 256 thr x 8.
// ---------------------------------------------------------------------------
__global__ __launch_bounds__(256) void k0_cvtW(const float* __restrict__ W,
                                               short* __restrict__ Wb) {
    const int i = (blockIdx.x * 256 + threadIdx.x) * 8;
    const float4 a0 = *(const float4*)(W + i);
    const float4 a1 = *(const float4*)(W + i + 4);
    bf16x8 v;
    v[0] = f2bf(a0.x); v[1] = f2bf(a0.y); v[2] = f2bf(a0.z); v[3] = f2bf(a0.w);
    v[4] = f2bf(a1.x); v[5] = f2bf(a1.y); v[6] = f2bf(a1.z); v[7] = f2bf(a1.w);
    *(bf16x8*)(Wb + i) = v;
}

// ---------------------------------------------------------------------------
// K1: logits = x @ W^T via MFMA bf16 + band-masked softmax -> wsm.
// 256 blocks x 256 thr (4 waves); wave handles strip t = blk*4+w, rows
// (t, b=0..15). A = x rows cvt'd to bf16 (m=lane&15, k=quad*8+j);
// B = Wb rows (n=lane&15, k=quad*8+j), 7 N-tiles of 16.
// D layout is determined AT RUNTIME by a probe MFMA (A=I, B[k][n]=k):
// probe acc == quad*4+reg  -> claimed layout  (row=quad*4+reg, col=lane&15)
// probe acc == lane&15     -> transposed      (row=lane&15, col=quad*4+reg)
// The probe algebra is invariant to any shared A/B k-permutation.
// ---------------------------------------------------------------------------
__global__ __launch_bounds__(256) void k1_mfma(const float* __restrict__ x,
                                               const short* __restrict__ Wb,
                                               float* __restrict__ wsm) {
    __shared__ __align__(16) float Llog[4][16 * LSTRIDE];
    __shared__ __align__(16) float Lout[4][16 * HK];

    const int tid = threadIdx.x;
    const int w = tid >> 6;
    const int lane = tid & 63;
    const int quad = lane >> 4;
    const int lr = lane & 15;
    const int strip = blockIdx.x * 4 + w;     // = t
    const int r0 = strip * 16;                // flat (t*B+b) row base

    // ---- layout probe ----
    bf16x8 ap, bp;
#pragma unroll
    for (int e = 0; e < 8; ++e) {
        const int k = quad * 8 + e;
        ap[e] = (k == lr) ? (short)0x3F80 : (short)0;   // A = I (first 16 k)
        bp[e] = f2bf((float)k);                          // B[k][n] = k
    }
    f32x4 pz = (f32x4){0.f, 0.f, 0.f, 0.f};
    pz = __builtin_amdgcn_mfma_f32_16x16x32_bf16(ap, bp, pz, 0, 0, 0);
    const bool claim = (pz[0] == (float)(quad * 4)) &&
                       (pz[1] == (float)(quad * 4 + 1));

    // ---- main GEMM ----
    const float* __restrict__ xa = x + (size_t)(r0 + lr) * CC + quad * 8;
    const short* __restrict__ wb = Wb + (size_t)lr * CC + quad * 8;

    f32x4 acc[7];
#pragma unroll
    for (int j = 0; j < 7; ++j) acc[j] = (f32x4){0.f, 0.f, 0.f, 0.f};

#pragma unroll 4
    for (int k0 = 0; k0 < CC; k0 += 32) {
        const float4 a0 = *(const float4*)(xa + k0);
        const float4 a1 = *(const float4*)(xa + k0 + 4);
        bf16x8 af;
        af[0] = f2bf(a0.x); af[1] = f2bf(a0.y); af[2] = f2bf(a0.z); af[3] = f2bf(a0.w);
        af[4] = f2bf(a1.x); af[5] = f2bf(a1.y); af[6] = f2bf(a1.z); af[7] = f2bf(a1.w);
#pragma unroll
        for (int j = 0; j < 7; ++j) {
            const bf16x8 bfrag = *(const bf16x8*)(wb + (size_t)(j * 16) * CC + k0);
            acc[j] = __builtin_amdgcn_mfma_f32_16x16x32_bf16(af, bfrag, acc[j], 0, 0, 0);
        }
    }

    // ---- scatter D into LDS with runtime-selected mapping ----
    // claimed: value = logits[row=quad*4+r][col(tile)=lr]
    // transposed: value = logits[row=lr][col(tile)=quad*4+r]
#pragma unroll
    for (int j = 0; j < 7; ++j)
#pragma unroll
        for (int r = 0; r < 4; ++r) {
            const int rowi = claim ? (quad * 4 + r) : lr;
            const int coli = claim ? lr : (quad * 4 + r);
            Llog[w][rowi * LSTRIDE + j * 16 + coli] = acc[j][r];
        }
    __syncthreads();

    // ---- masked softmax: 256 (row,head) pairs per wave, 4 per lane ----
    const int kmin = (strip >= PADL) ? 0 : (PADL - strip);
#pragma unroll
    for (int p = 0; p < 4; ++p) {
        const int idx = p * 64 + lane;        // 0..255
        const int m = idx >> 4;
        const int h = idx & 15;
        const float* lp = &Llog[w][m * LSTRIDE + h * KK];
        float a[KK];
#pragma unroll
        for (int k = 0; k < KK; ++k) a[k] = lp[k];

        float mx = -INFINITY;
#pragma unroll
        for (int k = 0; k < KK; ++k)
            if (k >= kmin) mx = fmaxf(mx, a[k]);
        float e[KK], s = 0.f;
#pragma unroll
        for (int k = 0; k < KK; ++k) {
            if (k >= kmin) { e[k] = expf(a[k] - mx); s += e[k]; }
            else           { e[k] = 0.f; }
        }
        const float inv = 1.f / s;
        float* op = &Lout[w][m * HK + h * KK];
#pragma unroll
        for (int k = 0; k < KK; ++k) op[k] = e[k] * inv;
    }
    __syncthreads();

    // ---- coalesced copy-out: 1792 contiguous floats -> wsm + r0*112 ----
    float* __restrict__ dst = wsm + (size_t)r0 * HK;
    const float* __restrict__ src = &Lout[w][0];
#pragma unroll
    for (int i = 0; i < 7; ++i) {
        const int o = i * 256 + lane * 4;
        *(float4*)(dst + o) = *(const float4*)(src + o);
    }
}

// ---------------------------------------------------------------------------
// K23: fused dense-stream + windowed sum, fillBuffer-shaped write path.
// k2 part per tile (bh, 16 rows):
//   1. hoist band gather: threads 0..111 load one wsm value (row=tid&15,
//      tap=tid>>4) into a register BEFORE the store loop — L2 latency hides
//      under the zero stream.
//   2. 16 branch-free plain dwordx4 zero stores per thread (64 KB/block,
//      identical shape to __amd_rocclr_fillBufferAligned which sustains
//      6.1 TB/s at 10% occupancy).
//   3. __syncthreads() (drains vmcnt -> zeros complete), then 112 scalar
//      band stores into the L2-hot lines. +28 B/row extra traffic (~0.1%).
// No nontemporal stores anywhere (the 6.1 TB/s fill uses plain stores;
// nt was an unverified variable from last round).
// blk%5==0 -> k3 block (4096), else k2 block (16384). grid = 20480.
// ---------------------------------------------------------------------------
__global__ __launch_bounds__(256) void k23_fused(const float* __restrict__ x,
                                                 const float* __restrict__ wsm,
                                                 float* __restrict__ dense,
                                                 float* __restrict__ out) {
    const int blk = blockIdx.x;

    if ((blk % 5) == 0) {
        // ---- k3 part: out[t,b,c] = sum_k wsm[t,b,h,k] * x[t+k-6,b,c] ----
        const int r0 = (blk / 5) << 2;        // 4 flat rows, same t
        const int t = r0 >> 4;
        const int c = threadIdx.x << 2;
        const int h = c >> 6;
        const int kmin = (t >= PADL) ? 0 : (PADL - t);

#pragma unroll
        for (int i = 0; i < 4; ++i) {
            const int row = r0 + i;
            const float* __restrict__ wp = wsm + ((size_t)row * HH + h) * KK;
            float w[KK];
#pragma unroll
            for (int k = 0; k < KK; ++k) w[k] = wp[k];

            f32x4 acc = (f32x4){0.f, 0.f, 0.f, 0.f};
            for (int k = kmin; k < KK; ++k) {
                const f32x4 xv = *(const f32x4*)(
                    x + ((size_t)row + (size_t)(k - PADL) * BB) * CC + c);
                acc[0] += w[k] * xv[0];
                acc[1] += w[k] * xv[1];
                acc[2] += w[k] * xv[2];
                acc[3] += w[k] * xv[3];
            }
            *(f32x4*)(out + (size_t)row * CC + c) = acc;
        }
    } else {
        // ---- k2 part: stream one 16x1024 tile of dense (bh, t0..t0+15) ----
        const int blk2 = blk - (blk / 5) - 1;  // 0..16383
        const int bh = blk2 >> 6;
        const int tc = blk2 & 63;
        const int b = bh >> 4;
        const int h = bh & 15;
        const int t0 = tc * 16;
        const int tid = threadIdx.x;

        // 1. hoisted band gather (112 active threads)
        const int r = tid & 15;                // row within tile
        const int j = tid >> 4;                // tap 0..15; active when <7
        const int t = t0 + r;
        const int cc = t - PADL + j;           // absolute column of this tap
        float bandv = 0.f;
        bool bandon = (j < KK) && (cc >= 0);   // cc <= t <= TT-1 always
        if (bandon)
            bandv = wsm[(((size_t)t * BB + b) * HH + h) * KK + j];

        // 2. branch-free zero stream: 16 rows x 4 KB, plain stores
        float* __restrict__ drow =
            dense + ((size_t)bh * TT + t0) * TT + (tid << 2);
        const f32x4 z = (f32x4){0.f, 0.f, 0.f, 0.f};
#pragma unroll
        for (int i = 0; i < 16; ++i) {
            *(f32x4*)drow = z;
            drow += TT;
        }

        // 3. zeros complete for the whole block, then band scatter
        __syncthreads();
        if (bandon)
            dense[((size_t)bh * TT + t) * TT + cc] = bandv;
    }
}

extern "C" void kernel_launch(void* const* d_in, const int* in_sizes, int n_in,
                              void* d_out, int out_size, void* d_ws, size_t ws_size,
                              hipStream_t stream) {
    const float* x = (const float*)d_in[0];   // (T, B, C)
    const float* W = (const float*)d_in[1];   // (H*K, C)
    float* out = (float*)d_out;                         // (T, B, C)
    float* dense = out + (size_t)TT * BB * CC;          // (B*H, T, T)
    float* wsm = (float*)d_ws;                          // (T, B, H, K)
    short* Wb = (short*)(wsm + (size_t)TT * BB * HK);   // bf16 W, 229 KB

    k0_cvtW<<<56, 256, 0, stream>>>(W, Wb);
    k1_mfma<<<256, 256, 0, stream>>>(x, Wb, wsm);
    k23_fused<<<5 * (TT * BB) / 4, 256, 0, stream>>>(x, wsm, dense, out);
}

// Round 3
// 1170.472 us; speedup vs baseline: 1.0495x; 1.0495x over previous
//
#include <hip/hip_runtime.h>
#include <math.h>

#define TT 1024
#define BB 16
#define CC 1024
#define HH 16
#define KK 7
#define PADL 6
#define HK 112          // H*K
#define LSTRIDE 116     // logits LDS row stride (floats)

typedef short bf16x8 __attribute__((ext_vector_type(8)));
typedef float f32x4 __attribute__((ext_vector_type(4)));

__device__ __forceinline__ short f2bf(float f) {
    union { float f; unsigned u; } v; v.f = f;
    unsigned r = v.u + 0x7fff + ((v.u >> 16) & 1);   // RNE; inputs finite
    return (short)(r >> 16);
}

// ---------------------------------------------------------------------------
// K0: W (112x1024 fp32) -> Wb (bf16). 114688 elems = 56 blocks x 256 thr x 8.
// ---------------------------------------------------------------------------
__global__ __launch_bounds__(256) void k0_cvtW(const float* __restrict__ W,
                                               short* __restrict__ Wb) {
    const int i = (blockIdx.x * 256 + threadIdx.x) * 8;
    const float4 a0 = *(const float4*)(W + i);
    const float4 a1 = *(const float4*)(W + i + 4);
    bf16x8 v;
    v[0] = f2bf(a0.x); v[1] = f2bf(a0.y); v[2] = f2bf(a0.z); v[3] = f2bf(a0.w);
    v[4] = f2bf(a1.x); v[5] = f2bf(a1.y); v[6] = f2bf(a1.z); v[7] = f2bf(a1.w);
    *(bf16x8*)(Wb + i) = v;
}

// ---------------------------------------------------------------------------
// K1: logits = x @ W^T via MFMA bf16 + band-masked softmax -> wsm.
// (unchanged from R1 — verified)
// ---------------------------------------------------------------------------
__global__ __launch_bounds__(256) void k1_mfma(const float* __restrict__ x,
                                               const short* __restrict__ Wb,
                                               float* __restrict__ wsm) {
    __shared__ __align__(16) float Llog[4][16 * LSTRIDE];
    __shared__ __align__(16) float Lout[4][16 * HK];

    const int tid = threadIdx.x;
    const int w = tid >> 6;
    const int lane = tid & 63;
    const int quad = lane >> 4;
    const int lr = lane & 15;
    const int strip = blockIdx.x * 4 + w;     // = t
    const int r0 = strip * 16;                // flat (t*B+b) row base

    // ---- layout probe ----
    bf16x8 ap, bp;
#pragma unroll
    for (int e = 0; e < 8; ++e) {
        const int k = quad * 8 + e;
        ap[e] = (k == lr) ? (short)0x3F80 : (short)0;   // A = I (first 16 k)
        bp[e] = f2bf((float)k);                          // B[k][n] = k
    }
    f32x4 pz = (f32x4){0.f, 0.f, 0.f, 0.f};
    pz = __builtin_amdgcn_mfma_f32_16x16x32_bf16(ap, bp, pz, 0, 0, 0);
    const bool claim = (pz[0] == (float)(quad * 4)) &&
                       (pz[1] == (float)(quad * 4 + 1));

    // ---- main GEMM ----
    const float* __restrict__ xa = x + (size_t)(r0 + lr) * CC + quad * 8;
    const short* __restrict__ wb = Wb + (size_t)lr * CC + quad * 8;

    f32x4 acc[7];
#pragma unroll
    for (int j = 0; j < 7; ++j) acc[j] = (f32x4){0.f, 0.f, 0.f, 0.f};

#pragma unroll 4
    for (int k0 = 0; k0 < CC; k0 += 32) {
        const float4 a0 = *(const float4*)(xa + k0);
        const float4 a1 = *(const float4*)(xa + k0 + 4);
        bf16x8 af;
        af[0] = f2bf(a0.x); af[1] = f2bf(a0.y); af[2] = f2bf(a0.z); af[3] = f2bf(a0.w);
        af[4] = f2bf(a1.x); af[5] = f2bf(a1.y); af[6] = f2bf(a1.z); af[7] = f2bf(a1.w);
#pragma unroll
        for (int j = 0; j < 7; ++j) {
            const bf16x8 bfrag = *(const bf16x8*)(wb + (size_t)(j * 16) * CC + k0);
            acc[j] = __builtin_amdgcn_mfma_f32_16x16x32_bf16(af, bfrag, acc[j], 0, 0, 0);
        }
    }

    // ---- scatter D into LDS with runtime-selected mapping ----
#pragma unroll
    for (int j = 0; j < 7; ++j)
#pragma unroll
        for (int r = 0; r < 4; ++r) {
            const int rowi = claim ? (quad * 4 + r) : lr;
            const int coli = claim ? lr : (quad * 4 + r);
            Llog[w][rowi * LSTRIDE + j * 16 + coli] = acc[j][r];
        }
    __syncthreads();

    // ---- masked softmax: 256 (row,head) pairs per wave, 4 per lane ----
    const int kmin = (strip >= PADL) ? 0 : (PADL - strip);
#pragma unroll
    for (int p = 0; p < 4; ++p) {
        const int idx = p * 64 + lane;        // 0..255
        const int m = idx >> 4;
        const int h = idx & 15;
        const float* lp = &Llog[w][m * LSTRIDE + h * KK];
        float a[KK];
#pragma unroll
        for (int k = 0; k < KK; ++k) a[k] = lp[k];

        float mx = -INFINITY;
#pragma unroll
        for (int k = 0; k < KK; ++k)
            if (k >= kmin) mx = fmaxf(mx, a[k]);
        float e[KK], s = 0.f;
#pragma unroll
        for (int k = 0; k < KK; ++k) {
            if (k >= kmin) { e[k] = expf(a[k] - mx); s += e[k]; }
            else           { e[k] = 0.f; }
        }
        const float inv = 1.f / s;
        float* op = &Lout[w][m * HK + h * KK];
#pragma unroll
        for (int k = 0; k < KK; ++k) op[k] = e[k] * inv;
    }
    __syncthreads();

    // ---- coalesced copy-out: 1792 contiguous floats -> wsm + r0*112 ----
    float* __restrict__ dst = wsm + (size_t)r0 * HK;
    const float* __restrict__ src = &Lout[w][0];
#pragma unroll
    for (int i = 0; i < 7; ++i) {
        const int o = i * 256 + lane * 4;
        *(float4*)(dst + o) = *(const float4*)(src + o);
    }
}

// ---------------------------------------------------------------------------
// K23: fused dense-stream + windowed sum (R1 structure, one change).
// R1 (best-known, 1175.9 us): single-pass predicated merge + nt stores.
// R3 change: the 112 band floats a k2-block needs (16 rows x 7 taps, shared
// across all threads of a row) are preloaded into LDS by 112 threads at
// block start + one LDS-only __syncthreads (issued BEFORE any store, so no
// vmcnt drain). The nt store stream then has zero global-load dependencies;
// in-band threads merge from LDS (ds_read, ~ns). Removes the L2-latency
// gather stalls that punctuated R1's store stream. R2's two-pass scatter
// (regressed +52 us: re-dirtied evicted lines -> RMW traffic, plus plain
// stores polluting L2) is abandoned.
// blk%5==0 -> k3 block (4096), else k2 block (16384). grid = 20480.
// ---------------------------------------------------------------------------
__global__ __launch_bounds__(256) void k23_fused(const float* __restrict__ x,
                                                 const float* __restrict__ wsm,
                                                 float* __restrict__ dense,
                                                 float* __restrict__ out) {
    __shared__ float Lband[16][8];   // 512 B; k2 path only
    const int blk = blockIdx.x;

    if ((blk % 5) == 0) {
        // ---- k3 part: out[t,b,c] = sum_k wsm[t,b,h,k] * x[t+k-6,b,c] ----
        const int r0 = (blk / 5) << 2;        // 4 flat rows, same t
        const int t = r0 >> 4;
        const int c = threadIdx.x << 2;
        const int h = c >> 6;
        const int kmin = (t >= PADL) ? 0 : (PADL - t);

#pragma unroll
        for (int i = 0; i < 4; ++i) {
            const int row = r0 + i;
            const float* __restrict__ wp = wsm + ((size_t)row * HH + h) * KK;
            float w[KK];
#pragma unroll
            for (int k = 0; k < KK; ++k) w[k] = wp[k];

            f32x4 acc = (f32x4){0.f, 0.f, 0.f, 0.f};
            for (int k = kmin; k < KK; ++k) {
                const f32x4 xv = *(const f32x4*)(
                    x + ((size_t)row + (size_t)(k - PADL) * BB) * CC + c);
                acc[0] += w[k] * xv[0];
                acc[1] += w[k] * xv[1];
                acc[2] += w[k] * xv[2];
                acc[3] += w[k] * xv[3];
            }
            __builtin_nontemporal_store(acc,
                (f32x4*)(out + (size_t)row * CC + c));
        }
    } else {
        // ---- k2 part: stream one 16x1024 tile of dense (bh, t0..t0+15) ----
        const int blk2 = blk - (blk / 5) - 1;  // 0..16383
        const int bh = blk2 >> 6;
        const int tc = blk2 & 63;
        const int b = bh >> 4;
        const int h = bh & 15;
        const int t0 = tc * 16;
        const int tid = threadIdx.x;

        // hoisted band gather -> LDS (112 threads, one float each)
        if (tid < 112) {
            const int r = tid & 15;            // row within tile
            const int j = tid >> 4;            // tap 0..6
            Lband[r][j] =
                wsm[(((size_t)(t0 + r) * BB + b) * HH + h) * KK + j];
        }
        __syncthreads();                       // LDS-only; before any store

        const int col = tid << 2;
        float* __restrict__ drow =
            dense + ((size_t)bh * TT + t0) * TT + col;

#pragma unroll
        for (int i = 0; i < 16; ++i) {
            const int t = t0 + i;
            const int lo = t - PADL;
            f32x4 v = (f32x4){0.f, 0.f, 0.f, 0.f};
            if (col + 3 >= lo && col <= t) {
#pragma unroll
                for (int j = 0; j < 4; ++j) {
                    const int cc = col + j;
                    if (cc >= lo && cc <= t && cc >= 0)
                        v[j] = Lband[i][cc - lo];
                }
            }
            __builtin_nontemporal_store(v, (f32x4*)drow);
            drow += TT;
        }
    }
}

extern "C" void kernel_launch(void* const* d_in, const int* in_sizes, int n_in,
                              void* d_out, int out_size, void* d_ws, size_t ws_size,
                              hipStream_t stream) {
    const float* x = (const float*)d_in[0];   // (T, B, C)
    const float* W = (const float*)d_in[1];   // (H*K, C)
    float* out = (float*)d_out;                         // (T, B, C)
    float* dense = out + (size_t)TT * BB * CC;          // (B*H, T, T)
    float* wsm = (float*)d_ws;                          // (T, B, H, K)
    short* Wb = (short*)(wsm + (size_t)TT * BB * HK);   // bf16 W, 229 KB

    k0_cvtW<<<56, 256, 0, stream>>>(W, Wb);
    k1_mfma<<<256, 256, 0, stream>>>(x, Wb, wsm);
    k23_fused<<<5 * (TT * BB) / 4, 256, 0, stream>>>(x, wsm, dense, out);
}